// Round 1
// baseline (101.487 us; speedup 1.0000x reference)
//
#include <hip/hip_runtime.h>
#include <math.h>

// Problem constants (setup_inputs): data1/data2 = (2, 4, 4096, 3) fp32, dim = 0.
constexpr int kB   = 2;
constexpr int kT   = 4;
constexpr int kBT  = kB * kT;       // 8 (b,t) slices
constexpr int kN   = 4096;          // points per slice (both sets)
constexpr int kR   = 4;             // set1 points per thread (register-tiled)
constexpr int kBLK = 256;           // threads per block
constexpr int kSP1 = kR * kBLK;     // 1024 set1 points per block
constexpr int kS1C = kN / kSP1;     // 4 set1 chunks
constexpr int kSP2 = 256;           // data2 points per block
constexpr int kS2C = kN / kSP2;     // 16 data2 chunks
constexpr int kNG  = kSP2 / 4;      // 64 groups of 4 data2 points (3 float4 each)

// Kernel 2: partial nearest-neighbor squared distances, combined with atomicMin
// on non-negative floats reinterpreted as uint (order-preserving, deterministic:
// min is exact/associative).
__global__ __launch_bounds__(kBLK) void hd_partial(
    const float* __restrict__ d1, const float* __restrict__ d2,
    unsigned int* __restrict__ ws)
{
    const int blk = blockIdx.x;
    const int c2  = blk % kS2C;
    const int t2  = blk / kS2C;
    const int c1  = t2 % kS1C;
    const int bt  = t2 / kS1C;

    const int tid = threadIdx.x;
    const int p0  = c1 * kSP1 + tid;
    const float* __restrict__ base1 = d1 + (size_t)bt * kN * 3;

    float x1[kR], y1[kR], z1[kR], q1[kR], m[kR];
#pragma unroll
    for (int k = 0; k < kR; ++k) {
        const int p = p0 + k * kBLK;
        const float x = base1[p * 3 + 0];
        const float y = base1[p * 3 + 1];
        const float z = base1[p * 3 + 2];
        x1[k] = x; y1[k] = y; z1[k] = z;
        q1[k] = fmaf(x, x, fmaf(y, y, z * z));
        m[k]  = 3.402823466e38f;
    }

    // data2 chunk: wave-uniform address, 4 points = 48 B = 3 aligned float4.
    // (bt*kN*3 and c2*kSP2*3 are multiples of 4 floats -> 16B aligned.)
    const float4* __restrict__ f4 =
        (const float4*)(d2 + (size_t)bt * kN * 3 + (size_t)c2 * kSP2 * 3);

#pragma unroll 2
    for (int g = 0; g < kNG; ++g) {
        const float4 A  = f4[3 * g + 0];
        const float4 Bv = f4[3 * g + 1];
        const float4 Cv = f4[3 * g + 2];
        const float px[4] = {A.x, A.w, Bv.z, Cv.y};
        const float py[4] = {A.y, Bv.x, Bv.w, Cv.z};
        const float pz[4] = {A.z, Bv.y, Cv.x, Cv.w};
#pragma unroll
        for (int j = 0; j < 4; ++j) {
            const float q2 = fmaf(px[j], px[j], fmaf(py[j], py[j], pz[j] * pz[j]));
#pragma unroll
            for (int k = 0; k < kR; ++k) {
                // d^2 = q1 + q2 - 2*dot ; track min(q2 - 2*dot), add q1 at the end.
                const float dot = fmaf(pz[j], z1[k], fmaf(py[j], y1[k], px[j] * x1[k]));
                m[k] = fminf(m[k], fmaf(-2.0f, dot, q2));
            }
        }
    }

    unsigned int* __restrict__ wsbt = ws + (size_t)bt * kN;
#pragma unroll
    for (int k = 0; k < kR; ++k) {
        // clamp cancellation-noise negatives so uint-compare == float-compare
        const float d2min = fmaxf(m[k] + q1[k], 0.0f);
        atomicMin(&wsbt[p0 + k * kBLK], __float_as_uint(d2min));
    }
}

// Kernel 3: per-batch sqrt + mean over (t, n) = 16384 values -> d_out[b].
__global__ __launch_bounds__(256) void hd_reduce(
    const unsigned int* __restrict__ ws, float* __restrict__ out)
{
    const int b   = blockIdx.x;            // 0..1
    const int tid = threadIdx.x;
    const float* __restrict__ w = (const float*)ws + (size_t)b * kT * kN;

    float s = 0.0f;
    for (int i = tid; i < kT * kN; i += 256)
        s += sqrtf(w[i]);                  // values already clamped >= 0

    // wave (64-lane) reduce
#pragma unroll
    for (int off = 32; off >= 1; off >>= 1)
        s += __shfl_down(s, off, 64);

    __shared__ float ls[4];
    if ((tid & 63) == 0) ls[tid >> 6] = s;
    __syncthreads();
    if (tid == 0) {
        float tot = ls[0] + ls[1] + ls[2] + ls[3];
        out[b] = tot * (1.0f / (kT * kN));
    }
}

extern "C" void kernel_launch(void* const* d_in, const int* in_sizes, int n_in,
                              void* d_out, int out_size, void* d_ws, size_t ws_size,
                              hipStream_t stream) {
    const float* d1 = (const float*)d_in[0];
    const float* d2 = (const float*)d_in[1];
    // d_in[2] is dim == 0 -> identity swapaxes; ignored.
    float* out = (float*)d_out;
    unsigned int* ws = (unsigned int*)d_ws;

    // Init per-point min slots to uint-max (atomicMin identity).
    hipMemsetAsync(d_ws, 0xFF, (size_t)kBT * kN * sizeof(unsigned int), stream);

    hd_partial<<<dim3(kBT * kS1C * kS2C), dim3(kBLK), 0, stream>>>(d1, d2, ws);
    hd_reduce<<<dim3(kB), dim3(256), 0, stream>>>(ws, out);
}

// Round 2
// 80.210 us; speedup vs baseline: 1.2653x; 1.2653x over previous
//
#include <hip/hip_runtime.h>
#include <math.h>

// Problem constants (setup_inputs): data1/data2 = (2, 4, 4096, 3) fp32, dim = 0.
constexpr int kB   = 2;
constexpr int kT   = 4;
constexpr int kBT  = kB * kT;       // 8 (b,t) slices
constexpr int kN   = 4096;          // points per slice (both sets)
constexpr int kR   = 4;             // set1 points per thread (register-tiled)
constexpr int kBLK = 256;           // threads per block
constexpr int kSP1 = kR * kBLK;     // 1024 set1 points per block
constexpr int kS1C = kN / kSP1;     // 4 set1 chunks
constexpr int kSP2 = 128;           // data2 points per block (chunk)
constexpr int kS2C = kN / kSP2;     // 32 data2 chunks
constexpr int kNG  = kSP2 / 4;      // 32 groups of 4 data2 points (3 float4 each)

// ws layout: partial mins, ws[c2][bt][p], c2 in [0,32), p in [0,4096)
//   -> 32*8*4096*4 B = 4 MB (plain stores, no atomics, no init needed).
// ws2 (after 4 MB): unused. Final mean accumulated via atomicAdd into d_out.

// Kernel 1: each block = one (bt, set1-chunk c1, data2-chunk c2).
// data2 chunk staged in LDS; per-thread kR=4 set1 points in registers.
// Inner math: s = q2 - 2*dot = d^2 - q1 via 3 fma (set1 pre-negated by -2),
// min-tracked; q1 added once in the epilogue. 4.25 VALU/pair.
__global__ __launch_bounds__(kBLK, 4) void hd_partial(
    const float* __restrict__ d1, const float* __restrict__ d2,
    float* __restrict__ ws)
{
    const int blk = blockIdx.x;
    const int c2  = blk % kS2C;
    const int t2  = blk / kS2C;
    const int c1  = t2 % kS1C;
    const int bt  = t2 / kS1C;

    const int tid = threadIdx.x;

    // Stage data2 chunk: 128 pts * 3 floats = 384 floats = 96 float4 (1.5 KB).
    __shared__ float4 s2[kSP2 * 3 / 4];
    const float4* __restrict__ g2 =
        (const float4*)(d2 + (size_t)bt * kN * 3 + (size_t)c2 * kSP2 * 3);
    if (tid < kSP2 * 3 / 4) s2[tid] = g2[tid];

    // Per-thread set1 points (registers), pre-scaled by -2 for the fma form.
    const int p0 = c1 * kSP1 + tid;
    const float* __restrict__ base1 = d1 + (size_t)bt * kN * 3;
    float nx[kR], ny[kR], nz[kR], q1[kR], m[kR];
#pragma unroll
    for (int k = 0; k < kR; ++k) {
        const int p = p0 + k * kBLK;
        const float x = base1[p * 3 + 0];
        const float y = base1[p * 3 + 1];
        const float z = base1[p * 3 + 2];
        nx[k] = -2.0f * x; ny[k] = -2.0f * y; nz[k] = -2.0f * z;
        q1[k] = fmaf(x, x, fmaf(y, y, z * z));
        m[k]  = 3.402823466e38f;
    }
    __syncthreads();

#pragma unroll 8
    for (int g = 0; g < kNG; ++g) {
        // 4 data2 points: 3 LDS float4 reads, same address across the wave
        // (broadcast, conflict-free).
        const float4 A  = s2[3 * g + 0];
        const float4 Bv = s2[3 * g + 1];
        const float4 Cv = s2[3 * g + 2];
        const float px[4] = {A.x, A.w, Bv.z, Cv.y};
        const float py[4] = {A.y, Bv.x, Bv.w, Cv.z};
        const float pz[4] = {A.z, Bv.y, Cv.x, Cv.w};
        float s[4][kR];
#pragma unroll
        for (int j = 0; j < 4; ++j) {
            const float q2 = fmaf(px[j], px[j], fmaf(py[j], py[j], pz[j] * pz[j]));
#pragma unroll
            for (int k = 0; k < kR; ++k) {
                float t = fmaf(px[j], nx[k], q2);
                t = fmaf(py[j], ny[k], t);
                s[j][k] = fmaf(pz[j], nz[k], t);
            }
        }
        // min3 fusion: 2 v_min3 per k per group (0.5 min/pair).
#pragma unroll
        for (int k = 0; k < kR; ++k) {
            m[k] = fminf(m[k], fminf(s[0][k], s[1][k]));
            m[k] = fminf(m[k], fminf(s[2][k], s[3][k]));
        }
    }

    // Coalesced partial-min store (d^2, clamped >= 0).
    float* __restrict__ wrow = ws + ((size_t)c2 * kBT + bt) * kN;
#pragma unroll
    for (int k = 0; k < kR; ++k)
        wrow[p0 + k * kBLK] = fmaxf(m[k] + q1[k], 0.0f);
}

// Kernel 2: 32 blocks (4 per bt). Min over the 32 chunk-partials, sqrt,
// block-sum, one atomicAdd per block into out[b] (pre-zeroed).
__global__ __launch_bounds__(256) void hd_reduce(
    const float* __restrict__ ws, float* __restrict__ out)
{
    const int bt   = blockIdx.x >> 2;     // 0..7
    const int quad = blockIdx.x & 3;      // 0..3 -> 1024 points each
    const int tid  = threadIdx.x;

    float sum = 0.0f;
#pragma unroll
    for (int i = 0; i < 4; ++i) {
        const int p = quad * 1024 + i * 256 + tid;
        float m = 3.402823466e38f;
#pragma unroll
        for (int c2 = 0; c2 < kS2C; ++c2)
            m = fminf(m, ws[((size_t)c2 * kBT + bt) * kN + p]);
        sum += sqrtf(m);
    }

    // wave (64-lane) reduce
#pragma unroll
    for (int off = 32; off >= 1; off >>= 1)
        sum += __shfl_down(sum, off, 64);

    __shared__ float ls[4];
    if ((tid & 63) == 0) ls[tid >> 6] = sum;
    __syncthreads();
    if (tid == 0) {
        const float tot = ls[0] + ls[1] + ls[2] + ls[3];
        atomicAdd(&out[bt >> 2], tot * (1.0f / (kT * kN)));
    }
}

extern "C" void kernel_launch(void* const* d_in, const int* in_sizes, int n_in,
                              void* d_out, int out_size, void* d_ws, size_t ws_size,
                              hipStream_t stream) {
    const float* d1 = (const float*)d_in[0];
    const float* d2 = (const float*)d_in[1];
    // d_in[2] is dim == 0 -> identity swapaxes; ignored.
    float* out = (float*)d_out;
    float* ws = (float*)d_ws;

    // d_out is poisoned 0xAA by the harness; zero it (accumulated via atomicAdd).
    hipMemsetAsync(d_out, 0, (size_t)kB * sizeof(float), stream);

    hd_partial<<<dim3(kBT * kS1C * kS2C), dim3(kBLK), 0, stream>>>(d1, d2, ws);
    hd_reduce<<<dim3(kBT * 4), dim3(256), 0, stream>>>(ws, out);
}

// Round 3
// 79.375 us; speedup vs baseline: 1.2786x; 1.0105x over previous
//
#include <hip/hip_runtime.h>
#include <math.h>

// Problem constants (setup_inputs): data1/data2 = (2, 4, 4096, 3) fp32, dim = 0.
constexpr int kB   = 2;
constexpr int kT   = 4;
constexpr int kBT  = kB * kT;       // 8 (b,t) slices
constexpr int kN   = 4096;          // points per slice (both sets)
constexpr int kR   = 4;             // set1 points per thread (register-tiled)
constexpr int kBLK = 256;           // threads per block
constexpr int kSP1 = kR * kBLK;     // 1024 set1 points per block
constexpr int kS1C = kN / kSP1;     // 4 set1 chunks
constexpr int kSP2 = 128;           // data2 points per block (chunk)
constexpr int kS2C = kN / kSP2;     // 32 data2 chunks
constexpr int kNG  = kSP2 / 4;      // 32 groups of 4 data2 points (3 float4 each)

// ws layout: partial mins ws[c2][bt][p], c2 in [0,32), p in [0,4096) -> 4 MB.
// Plain coalesced stores (no atomics, no init). Mean accumulated into d_out
// via one atomicAdd per reduce block; d_out zeroed by hd_partial block 0.

// Kernel 1: one block per (bt, set1-chunk c1, data2-chunk c2).
// data2 chunk read via BLOCK-UNIFORM addresses (no threadIdx in the address
// math) -> backend scalarizes to s_load; coords live in SGPRs, feeding the
// dot-product fmas directly (1 SGPR operand per VALU instr — legal).
// Inner math: s = q2 - 2*dot = d^2 - q1 via 3 fma (set1 pre-scaled by -2);
// q1 added once in the epilogue. 4.25 VALU instr/pair, zero LDS traffic.
__global__ __launch_bounds__(kBLK, 4) void hd_partial(
    const float* __restrict__ d1, const float* __restrict__ d2,
    float* __restrict__ ws, float* __restrict__ out)
{
    const int blk = blockIdx.x;
    const int c2  = blk % kS2C;
    const int t2  = blk / kS2C;
    const int c1  = t2 % kS1C;
    const int bt  = t2 / kS1C;

    const int tid = threadIdx.x;

    // Zero the 2 output accumulators (poisoned 0xAA by the harness each iter).
    // Stream order guarantees this retires before hd_reduce's atomicAdds.
    if (blk == 0 && tid < kB) out[tid] = 0.0f;

    // Per-thread set1 points (registers), pre-scaled by -2 for the fma form.
    const int p0 = c1 * kSP1 + tid;
    const float* __restrict__ base1 = d1 + (size_t)bt * kN * 3;
    float nx[kR], ny[kR], nz[kR], q1[kR], m[kR];
#pragma unroll
    for (int k = 0; k < kR; ++k) {
        const int p = p0 + k * kBLK;
        const float x = base1[p * 3 + 0];
        const float y = base1[p * 3 + 1];
        const float z = base1[p * 3 + 2];
        nx[k] = -2.0f * x; ny[k] = -2.0f * y; nz[k] = -2.0f * z;
        q1[k] = fmaf(x, x, fmaf(y, y, z * z));
        m[k]  = 3.402823466e38f;
    }

    // data2 chunk: 128 pts * 3 floats = 96 float4, all block-uniform, 16B
    // aligned (bt*12288 and c2*384 floats are multiples of 4).
    const float4* __restrict__ g2 =
        (const float4*)(d2 + (size_t)bt * kN * 3 + (size_t)c2 * kSP2 * 3);

#pragma unroll 4
    for (int g = 0; g < kNG; ++g) {
        const float4 A  = g2[3 * g + 0];
        const float4 Bv = g2[3 * g + 1];
        const float4 Cv = g2[3 * g + 2];
        const float px[4] = {A.x, A.w, Bv.z, Cv.y};
        const float py[4] = {A.y, Bv.x, Bv.w, Cv.z};
        const float pz[4] = {A.z, Bv.y, Cv.x, Cv.w};
        float s[4][kR];
#pragma unroll
        for (int j = 0; j < 4; ++j) {
            // q2 in a VGPR (wave-uniform value; avoids 2-SGPR operand limit
            // in the dot fmas below).
            const float q2 = fmaf(px[j], px[j], fmaf(py[j], py[j], pz[j] * pz[j]));
#pragma unroll
            for (int k = 0; k < kR; ++k) {
                float t = fmaf(px[j], nx[k], q2);
                t = fmaf(py[j], ny[k], t);
                s[j][k] = fmaf(pz[j], nz[k], t);
            }
        }
        // v_min3 formation: 2 three-input mins per k per group.
#pragma unroll
        for (int k = 0; k < kR; ++k) {
            m[k] = fminf(m[k], fminf(s[0][k], s[1][k]));
            m[k] = fminf(m[k], fminf(s[2][k], s[3][k]));
        }
    }

    // Coalesced partial-min store (d^2, clamped >= 0 so sqrt is safe).
    float* __restrict__ wrow = ws + ((size_t)c2 * kBT + bt) * kN;
#pragma unroll
    for (int k = 0; k < kR; ++k)
        wrow[p0 + k * kBLK] = fmaxf(m[k] + q1[k], 0.0f);
}

// Kernel 2: 32 blocks (4 per bt). float4 min over the 32 chunk-partials,
// sqrt, block-sum, one atomicAdd per block into out[b].
__global__ __launch_bounds__(256) void hd_reduce(
    const float4* __restrict__ ws4, float* __restrict__ out)
{
    const int bt   = blockIdx.x >> 2;     // 0..7
    const int quad = blockIdx.x & 3;      // 0..3 -> 1024 points each
    const int tid  = threadIdx.x;

    const int p4 = quad * 256 + tid;      // float4 index within the 1024-f4 row
    float4 m4 = make_float4(3.402823466e38f, 3.402823466e38f,
                            3.402823466e38f, 3.402823466e38f);
#pragma unroll 8
    for (int c2 = 0; c2 < kS2C; ++c2) {
        const float4 v = ws4[((size_t)c2 * kBT + bt) * (kN / 4) + p4];
        m4.x = fminf(m4.x, v.x);
        m4.y = fminf(m4.y, v.y);
        m4.z = fminf(m4.z, v.z);
        m4.w = fminf(m4.w, v.w);
    }
    float sum = sqrtf(m4.x) + sqrtf(m4.y) + sqrtf(m4.z) + sqrtf(m4.w);

    // wave (64-lane) reduce
#pragma unroll
    for (int off = 32; off >= 1; off >>= 1)
        sum += __shfl_down(sum, off, 64);

    __shared__ float ls[4];
    if ((tid & 63) == 0) ls[tid >> 6] = sum;
    __syncthreads();
    if (tid == 0) {
        const float tot = ls[0] + ls[1] + ls[2] + ls[3];
        atomicAdd(&out[bt >> 2], tot * (1.0f / (kT * kN)));
    }
}

extern "C" void kernel_launch(void* const* d_in, const int* in_sizes, int n_in,
                              void* d_out, int out_size, void* d_ws, size_t ws_size,
                              hipStream_t stream) {
    const float* d1 = (const float*)d_in[0];
    const float* d2 = (const float*)d_in[1];
    // d_in[2] is dim == 0 -> identity swapaxes; ignored.
    float* out = (float*)d_out;
    float* ws = (float*)d_ws;

    hd_partial<<<dim3(kBT * kS1C * kS2C), dim3(kBLK), 0, stream>>>(d1, d2, ws, out);
    hd_reduce<<<dim3(kBT * 4), dim3(256), 0, stream>>>((const float4*)ws, out);
}